// Round 1
// baseline (330.013 us; speedup 1.0000x reference)
//
#include <hip/hip_runtime.h>
#include <hip/hip_fp16.h>
#include <stdint.h>

#define PATCH_PIX 9216
#define PH 96
#define PW 96

// 1D gaussian (WS=11, sigma=1.5), normalized to sum 1 (matches reference _window)
__device__ __forceinline__ void gauss_weights(float g[11]) {
  float s = 0.f;
#pragma unroll
  for (int j = 0; j < 11; ++j) {
    float d = (float)(j - 5);
    g[j] = __expf(-(d * d) / 4.5f);
    s += g[j];
  }
  float inv = 1.f / s;
#pragma unroll
  for (int j = 0; j < 11; ++j) g[j] *= inv;
}

// Kernel A: horizontal gaussian of {p, t, p^2, t^2, p*t} -> packed f16 buffers.
// Also fused: per-pixel BCE + target-sum, wave-reduced, atomically accumulated per patch.
// Thread mapping: t -> (local patch l, row r, 4-col group c). 2304 threads per patch (96*24),
// 2304 % 64 == 0 so every wave lives in exactly one patch.
__global__ __launch_bounds__(256) void kA(
    const float* __restrict__ pred, const float* __restrict__ tgt,
    float* __restrict__ accum,
    uint32_t* __restrict__ hA, uint32_t* __restrict__ hB, __half* __restrict__ hC,
    int poff, int pc)
{
  int t = blockIdx.x * 256 + threadIdx.x;
  int l = t / 2304;
  if (l >= pc) return;
  int rem = t - l * 2304;
  int r = rem / 24;
  int c = rem - r * 24;
  int gpid = poff + l;

  const float* prow = pred + (size_t)gpid * PATCH_PIX + r * PW;
  const float* trow = tgt  + (size_t)gpid * PATCH_PIX + r * PW;

  // Load floats [x0-8 .. x0+11] (x0 = 4c) as 5 aligned float4 chunks; out-of-range -> 0 (zero pad).
  float p[20], q[20];
#pragma unroll
  for (int cc = 0; cc < 5; ++cc) {
    int ch = c - 2 + cc;
    float4 vp = make_float4(0.f, 0.f, 0.f, 0.f);
    float4 vt = make_float4(0.f, 0.f, 0.f, 0.f);
    if (ch >= 0 && ch < 24) {
      vp = reinterpret_cast<const float4*>(prow)[ch];
      vt = reinterpret_cast<const float4*>(trow)[ch];
    }
    p[4*cc+0] = vp.x; p[4*cc+1] = vp.y; p[4*cc+2] = vp.z; p[4*cc+3] = vp.w;
    q[4*cc+0] = vt.x; q[4*cc+1] = vt.y; q[4*cc+2] = vt.z; q[4*cc+3] = vt.w;
  }

  float g[11];
  gauss_weights(g);

  // squares/products once per loaded pixel (indices 3..16 are the tap range)
  float pp[14], tt[14], pt[14];
#pragma unroll
  for (int i = 0; i < 14; ++i) {
    float a = p[3+i], b = q[3+i];
    pp[i] = a * a; tt[i] = b * b; pt[i] = a * b;
  }

  uint32_t oa[4], ob[4];
  uint16_t oc[4];
#pragma unroll
  for (int k = 0; k < 4; ++k) {
    float a = 0.f, b = 0.f, d = 0.f, e = 0.f, f = 0.f;
#pragma unroll
    for (int j = 0; j < 11; ++j) {
      float w = g[j];
      a = fmaf(w, p[3+k+j], a);
      b = fmaf(w, q[3+k+j], b);
      d = fmaf(w, pp[k+j], d);
      e = fmaf(w, tt[k+j], e);
      f = fmaf(w, pt[k+j], f);
    }
    __half2 a2 = __float22half2_rn(make_float2(a, b));
    __half2 b2 = __float22half2_rn(make_float2(d, e));
    oa[k] = *reinterpret_cast<uint32_t*>(&a2);
    ob[k] = *reinterpret_cast<uint32_t*>(&b2);
    __half cv = __float2half_rn(f);
    oc[k] = *reinterpret_cast<uint16_t*>(&cv);
  }
  size_t i0 = (size_t)l * PATCH_PIX + (size_t)r * PW + (size_t)c * 4;
  *reinterpret_cast<uint4*>(hA + i0) = make_uint4(oa[0], oa[1], oa[2], oa[3]);
  *reinterpret_cast<uint4*>(hB + i0) = make_uint4(ob[0], ob[1], ob[2], ob[3]);
  uint32_t c01 = (uint32_t)oc[0] | ((uint32_t)oc[1] << 16);
  uint32_t c23 = (uint32_t)oc[2] | ((uint32_t)oc[3] << 16);
  *reinterpret_cast<uint2*>(hC + i0) = make_uint2(c01, c23);

  // ---- fused BCE + target sum on the 4 owned pixels (array idx 8..11) ----
  float bce = 0.f, ts = 0.f;
#pragma unroll
  for (int k = 0; k < 4; ++k) {
    float pv = p[8+k], tv = q[8+k];
    float lp = fmaxf(__logf(pv), -100.f);
    float l1 = fmaxf(__logf(1.f - pv), -100.f);
    bce += -(tv * lp + (1.f - tv) * l1);
    ts  += tv;
  }
#pragma unroll
  for (int o = 32; o; o >>= 1) {
    bce += __shfl_down(bce, o);
    ts  += __shfl_down(ts, o);
  }
  if ((threadIdx.x & 63) == 0) {
    atomicAdd(&accum[(size_t)gpid * 4 + 0], bce);
    atomicAdd(&accum[(size_t)gpid * 4 + 1], ts);
  }
}

// Kernel B: vertical 11-row box (rolling, register ring) + SSIM map + per-patch sum.
// Thread = (local patch, column x).
__global__ __launch_bounds__(256) void kB(
    const uint32_t* __restrict__ hA, const uint32_t* __restrict__ hB,
    const __half* __restrict__ hC,
    float* __restrict__ accum, int poff, int pc)
{
  int t = blockIdx.x * 256 + threadIdx.x;
  if (t >= pc * PW) return;
  int l = t / PW;
  int x = t - l * PW;
  size_t base = (size_t)l * PATCH_PIX + x;

  const float C1 = 1e-4f, C2 = 9e-4f;
  float sp = 0.f, st = 0.f, spp = 0.f, stt = 0.f, spt = 0.f;
  float rg[11][5];
  float ssum = 0.f;

#define LOAD5(ROW, V0, V1, V2, V3, V4) do { \
    size_t _i = base + (size_t)(ROW) * PW; \
    uint32_t _ua = hA[_i]; uint32_t _ub = hB[_i]; __half _hc = hC[_i]; \
    __half2 _ha = *reinterpret_cast<__half2*>(&_ua); \
    __half2 _hb = *reinterpret_cast<__half2*>(&_ub); \
    float2 _fa = __half22float2(_ha); float2 _fb = __half22float2(_hb); \
    V0 = _fa.x; V1 = _fa.y; V2 = _fb.x; V3 = _fb.y; V4 = __half2float(_hc); \
  } while (0)

  // prologue: rows 0..4
#pragma unroll
  for (int r = 0; r < 5; ++r) {
    LOAD5(r, rg[r][0], rg[r][1], rg[r][2], rg[r][3], rg[r][4]);
    sp += rg[r][0]; st += rg[r][1]; spp += rg[r][2]; stt += rg[r][3]; spt += rg[r][4];
  }

#pragma unroll
  for (int y = 0; y < 96; ++y) {
    if (y >= 6) {
      const int s = (y - 6) % 11;
      sp -= rg[s][0]; st -= rg[s][1]; spp -= rg[s][2]; stt -= rg[s][3]; spt -= rg[s][4];
    }
    if (y + 5 < 96) {
      const int s = (y + 5) % 11;
      LOAD5(y + 5, rg[s][0], rg[s][1], rg[s][2], rg[s][3], rg[s][4]);
      sp += rg[s][0]; st += rg[s][1]; spp += rg[s][2]; stt += rg[s][3]; spt += rg[s][4];
    }
    float m11 = sp * sp, m22 = st * st, m12 = sp * st;
    float num = (2.f * m12 + C1) * (2.f * (spt - m12) + C2);
    float den = (m11 + m22 + C1) * ((spp - m11) + (stt - m22) + C2);
    ssum += __fdividef(num, den);
  }
#undef LOAD5

  atomicAdd(&accum[(size_t)(poff + l) * 4 + 2], ssum);
}

// Kernel C: masked mean over patches -> scalar
__global__ __launch_bounds__(256) void kC(
    const float* __restrict__ accum, const int* __restrict__ mask,
    float* __restrict__ out, int N)
{
  int tid = threadIdx.x;
  float tot = 0.f, cnt = 0.f;
  const float inv = 1.f / (float)PATCH_PIX;
  for (int i = tid; i < N; i += 256) {
    float bce = accum[(size_t)i * 4 + 0];
    float ts  = accum[(size_t)i * 4 + 1];
    float ss  = accum[(size_t)i * 4 + 2];
    bool valid = (mask[i] != 0) && (ts >= 1e-6f);
    float loss = 0.5f * (bce * inv) + 0.5f * (1.f - ss * inv);
    if (valid) { tot += loss; cnt += 1.f; }
  }
  __shared__ float sT[256], sC[256];
  sT[tid] = tot; sC[tid] = cnt;
  __syncthreads();
  for (int o = 128; o; o >>= 1) {
    if (tid < o) { sT[tid] += sT[tid + o]; sC[tid] += sC[tid + o]; }
    __syncthreads();
  }
  if (tid == 0) out[0] = (sC[0] > 0.f) ? (sT[0] / sC[0]) : 0.f;
}

extern "C" void kernel_launch(void* const* d_in, const int* in_sizes, int n_in,
                              void* d_out, int out_size, void* d_ws, size_t ws_size,
                              hipStream_t stream) {
  const float* pred = (const float*)d_in[0];
  const float* tgt  = (const float*)d_in[1];
  const int*   mask = (const int*)d_in[2];
  int N = in_sizes[2];  // 2048 patches

  float* accum = (float*)d_ws;               // N * 4 floats
  const size_t accum_res = 65536;
  char* hbase = (char*)d_ws + accum_res;
  size_t avail = (ws_size > accum_res) ? (ws_size - accum_res) : 0;

  // chunk patches so the f16 intermediate (10 B/pixel) fits in the workspace
  int pc = N;
  while (pc > 1 && (size_t)pc * PATCH_PIX * 10ull > avail) pc >>= 1;

  hipMemsetAsync(accum, 0, (size_t)N * 4 * sizeof(float), stream);

  for (int off = 0; off < N; off += pc) {
    int cur = (N - off < pc) ? (N - off) : pc;
    uint32_t* hA = (uint32_t*)hbase;
    uint32_t* hB = (uint32_t*)(hbase + (size_t)cur * PATCH_PIX * 4);
    __half*   hC = (__half*)  (hbase + (size_t)cur * PATCH_PIX * 8);

    int nthreadsA = cur * 2304;
    int blocksA = (nthreadsA + 255) / 256;
    kA<<<blocksA, 256, 0, stream>>>(pred, tgt, accum, hA, hB, hC, off, cur);

    int nthreadsB = cur * PW;
    int blocksB = (nthreadsB + 255) / 256;
    kB<<<blocksB, 256, 0, stream>>>(hA, hB, hC, accum, off, cur);
  }

  kC<<<1, 256, 0, stream>>>(accum, mask, (float*)d_out, N);
}

// Round 2
// 278.888 us; speedup vs baseline: 1.1833x; 1.1833x over previous
//
#include <hip/hip_runtime.h>
#include <hip/hip_fp16.h>
#include <stdint.h>

#define PW 96
#define PH 96
#define PIX 9216
#define PSTR 97   // padded LDS row stride (97 mod 32 = 1 -> conflict-free phase A)

// Gaussian weights (WS=11, sigma=1.5, normalized to sum 1) precomputed as literals.
#define GW0 1.02838e-03f
#define GW1 7.59876e-03f
#define GW2 3.60008e-02f
#define GW3 1.09361e-01f
#define GW4 2.13006e-01f
#define GW5 2.66012e-01f

__global__ __launch_bounds__(768) void fused_kernel(
    const float* __restrict__ pred, const float* __restrict__ tgt,
    float* __restrict__ accum)
{
  constexpr float G[11] = {GW0, GW1, GW2, GW3, GW4, GW5, GW4, GW3, GW2, GW1, GW0};

  __shared__ __half2 s_pt[PH * PSTR];   // (p, t)
  __shared__ __half2 s_ab[PH * PSTR];   // (h*p, h*t)
  __shared__ __half2 s_de[PH * PSTR];   // (h*pp, h*tt)
  __shared__ __half  s_c [PH * PSTR];   // h*pt
  __shared__ float redA[12], redB[12], redC[12];

  const int pid = blockIdx.x;
  const int tid = threadIdx.x;
  const float4* p4 = reinterpret_cast<const float4*>(pred + (size_t)pid * PIX);
  const float4* t4 = reinterpret_cast<const float4*>(tgt  + (size_t)pid * PIX);

  // ---- Phase 0: coalesced load -> LDS half2, fused BCE + target-sum ----
  float bce = 0.f, ts = 0.f;
#pragma unroll
  for (int i = 0; i < 3; ++i) {
    int f = tid + i * 768;            // float4 index 0..2303
    float4 vp = p4[f];
    float4 vt = t4[f];
    int row = f / 24;
    int col = (f - row * 24) * 4;
    int o = row * PSTR + col;
    s_pt[o + 0] = __floats2half2_rn(vp.x, vt.x);
    s_pt[o + 1] = __floats2half2_rn(vp.y, vt.y);
    s_pt[o + 2] = __floats2half2_rn(vp.z, vt.z);
    s_pt[o + 3] = __floats2half2_rn(vp.w, vt.w);
    const float pv[4] = {vp.x, vp.y, vp.z, vp.w};
    const float tv[4] = {vt.x, vt.y, vt.z, vt.w};
#pragma unroll
    for (int k = 0; k < 4; ++k) {
      float lp = fmaxf(__logf(pv[k]), -100.f);
      float l1 = fmaxf(__logf(1.f - pv[k]), -100.f);
      bce -= tv[k] * lp + (1.f - tv[k]) * l1;
      ts += tv[k];
    }
  }
  __syncthreads();

  // ---- Phase A: horizontal gaussian of {p,t,pp,tt,pt}, f32 accum -> f16 LDS ----
  {
    int r  = tid >> 3;                // row 0..95
    int x0 = (tid & 7) * 12;          // 12 output px per thread
    int rb = r * PSTR;
    float a[12], b[12], d[12], e[12], f5[12];
#pragma unroll
    for (int k = 0; k < 12; ++k) { a[k] = b[k] = d[k] = e[k] = f5[k] = 0.f; }
#pragma unroll
    for (int j = 0; j < 22; ++j) {    // input elements x0-5 .. x0+16
      int x = x0 + j - 5;
      __half2 h = (x >= 0 && x < PW) ? s_pt[rb + x] : __floats2half2_rn(0.f, 0.f);
      float2 v = __half22float2(h);
      float pv = v.x, tv = v.y;
      float pp = pv * pv, tt = tv * tv, pq = pv * tv;
#pragma unroll
      for (int k = 0; k < 12; ++k) {  // static bounds: element j feeds k in [j-10, j]
        if (k >= j - 10 && k <= j && k <= 11) {
          float w = G[j - k];
          a[k]  = fmaf(w, pv, a[k]);
          b[k]  = fmaf(w, tv, b[k]);
          d[k]  = fmaf(w, pp, d[k]);
          e[k]  = fmaf(w, tt, e[k]);
          f5[k] = fmaf(w, pq, f5[k]);
        }
      }
    }
#pragma unroll
    for (int k = 0; k < 12; ++k) {
      int o = rb + x0 + k;
      s_ab[o] = __floats2half2_rn(a[k], b[k]);
      s_de[o] = __floats2half2_rn(d[k], e[k]);
      s_c[o]  = __float2half_rn(f5[k]);
    }
  }
  __syncthreads();

  // ---- Phase B: vertical 11-row running box + SSIM ----
  float ssum = 0.f;
  {
    int s  = tid / 96;                // strip 0..7 (12 rows each)
    int x  = tid - s * 96;            // column 0..95
    int y0 = s * 12;
    float sa = 0.f, sb = 0.f, sd = 0.f, se = 0.f, sc = 0.f;

#define RLD(R, OP) do { \
      int _o = (R) * PSTR + x; \
      float2 _va = __half22float2(s_ab[_o]); \
      float2 _vd = __half22float2(s_de[_o]); \
      float  _vc = __half2float(s_c[_o]); \
      sa OP _va.x; sb OP _va.y; sd OP _vd.x; se OP _vd.y; sc OP _vc; \
    } while (0)

#pragma unroll
    for (int r = -5; r < 5; ++r) {    // init window rows y0-5 .. y0+4 (clipped)
      int rr = y0 + r;
      if (rr >= 0) RLD(rr, +=);
    }
#pragma unroll
    for (int i = 0; i < 12; ++i) {
      int y = y0 + i;
      int ya = y + 5;
      if (ya < PH) RLD(ya, +=);       // window now [y-5, y+5] (clipped)
      float m11 = sa * sa, m22 = sb * sb, m12 = sa * sb;
      float num = (2.f * m12 + 1e-4f) * (2.f * (sc - m12) + 9e-4f);
      float den = (m11 + m22 + 1e-4f) * ((sd - m11) + (se - m22) + 9e-4f);
      ssum += __fdividef(num, den);
      int yr = y - 5;
      if (yr >= 0) RLD(yr, -=);
    }
#undef RLD
  }

  // ---- block reduction (block owns patch -> plain stores, no atomics) ----
  int lane = tid & 63;
  int w = tid >> 6;
#pragma unroll
  for (int o = 32; o; o >>= 1) {
    bce  += __shfl_down(bce, o);
    ts   += __shfl_down(ts, o);
    ssum += __shfl_down(ssum, o);
  }
  if (lane == 0) { redA[w] = bce; redB[w] = ts; redC[w] = ssum; }
  __syncthreads();
  if (tid == 0) {
    float A = 0.f, B = 0.f, C = 0.f;
#pragma unroll
    for (int i = 0; i < 12; ++i) { A += redA[i]; B += redB[i]; C += redC[i]; }
    float* out = accum + (size_t)pid * 4;
    out[0] = A; out[1] = B; out[2] = C;
  }
}

// masked mean over patches -> scalar
__global__ __launch_bounds__(256) void kC(
    const float* __restrict__ accum, const int* __restrict__ mask,
    float* __restrict__ out, int N)
{
  int tid = threadIdx.x;
  float tot = 0.f, cnt = 0.f;
  const float inv = 1.f / (float)PIX;
  for (int i = tid; i < N; i += 256) {
    float bce = accum[(size_t)i * 4 + 0];
    float tsv = accum[(size_t)i * 4 + 1];
    float ssv = accum[(size_t)i * 4 + 2];
    bool valid = (mask[i] != 0) && (tsv >= 1e-6f);
    float loss = 0.5f * (bce * inv) + 0.5f * (1.f - ssv * inv);
    if (valid) { tot += loss; cnt += 1.f; }
  }
  __shared__ float sT[256], sC[256];
  sT[tid] = tot; sC[tid] = cnt;
  __syncthreads();
  for (int o = 128; o; o >>= 1) {
    if (tid < o) { sT[tid] += sT[tid + o]; sC[tid] += sC[tid + o]; }
    __syncthreads();
  }
  if (tid == 0) out[0] = (sC[0] > 0.f) ? (sT[0] / sC[0]) : 0.f;
}

extern "C" void kernel_launch(void* const* d_in, const int* in_sizes, int n_in,
                              void* d_out, int out_size, void* d_ws, size_t ws_size,
                              hipStream_t stream) {
  const float* pred = (const float*)d_in[0];
  const float* tgt  = (const float*)d_in[1];
  const int*   mask = (const int*)d_in[2];
  int N = in_sizes[2];  // 2048 patches

  float* accum = (float*)d_ws;  // N*4 floats, fully written by fused_kernel
  fused_kernel<<<N, 768, 0, stream>>>(pred, tgt, accum);
  kC<<<1, 256, 0, stream>>>(accum, mask, (float*)d_out, N);
}

// Round 3
// 257.870 us; speedup vs baseline: 1.2798x; 1.0815x over previous
//
#include <hip/hip_runtime.h>
#include <hip/hip_fp16.h>
#include <stdint.h>

#define PW   96
#define PH   96
#define PIX  9216
#define ROWS 24            // owned rows per block
#define HR   34            // rows incl. 5-row halo each side
#define PSTR 108           // s_pt stride (mult of 4 dwords; data at cols 5..100)
#define NT   384

// Gaussian weights (WS=11, sigma=1.5, normalized; verified absmax 0.0 in R1/R2)
#define GW0 1.02838e-03f
#define GW1 7.59876e-03f
#define GW2 3.60008e-02f
#define GW3 1.09361e-01f
#define GW4 2.13006e-01f
#define GW5 2.66012e-01f

__global__ __launch_bounds__(NT) void fused(
    const float* __restrict__ pred, const float* __restrict__ tgt,
    float* __restrict__ accum)
{
  constexpr float G[11] = {GW0, GW1, GW2, GW3, GW4, GW5, GW4, GW3, GW2, GW1, GW0};

  __shared__ __half2 s_pt[HR * PSTR];  // (p,t), x-padded with zeros
  __shared__ __half2 s_ab[HR * PW];    // (h*p, h*t)
  __shared__ __half2 s_de[HR * PW];    // (h*pp, h*tt)
  __shared__ __half  s_c [HR * PW];    // h*pt
  __shared__ float   red[6][3];

  const int b   = blockIdx.x;
  const int pid = b >> 2;
  const int sub = b & 3;
  const int y0  = sub * ROWS;
  const int tid = threadIdx.x;

  const float4* p4 = reinterpret_cast<const float4*>(pred + (size_t)pid * PIX);
  const float4* t4 = reinterpret_cast<const float4*>(tgt  + (size_t)pid * PIX);

  float bce = 0.f, ts = 0.f;

  // ---- Phase 0: load rows y0-5..y0+28 -> LDS half2; fused BCE on owned rows ----
#pragma unroll
  for (int i = 0; i < 3; ++i) {
    int f = tid + i * NT;              // float4-slot id, 34*24 = 816 total
    if (f < HR * 24) {
      int lr = f / 24, c = f - lr * 24;
      int gy = y0 - 5 + lr;
      float4 vp = make_float4(0.f, 0.f, 0.f, 0.f);
      float4 vt = make_float4(0.f, 0.f, 0.f, 0.f);
      if (gy >= 0 && gy < PH) { vp = p4[gy * 24 + c]; vt = t4[gy * 24 + c]; }
      __half2* dst = &s_pt[lr * PSTR + 5 + c * 4];
      dst[0] = __floats2half2_rn(vp.x, vt.x);
      dst[1] = __floats2half2_rn(vp.y, vt.y);
      dst[2] = __floats2half2_rn(vp.z, vt.z);
      dst[3] = __floats2half2_rn(vp.w, vt.w);
      if (lr >= 5 && lr < 5 + ROWS) {  // owned rows only (always in-bounds)
        const float pv[4] = {vp.x, vp.y, vp.z, vp.w};
        const float tv[4] = {vt.x, vt.y, vt.z, vt.w};
#pragma unroll
        for (int k = 0; k < 4; ++k) {
          float lp = fmaxf(__logf(pv[k]), -100.f);
          float l1 = fmaxf(__logf(1.f - pv[k]), -100.f);
          bce -= tv[k] * lp + (1.f - tv[k]) * l1;
          ts  += tv[k];
        }
      }
    }
  }
  // zero the x-halo columns (0..4 and 101..105)
  if (tid < HR * 10) {
    int lr = tid / 10, c = tid - lr * 10;
    int col = (c < 5) ? c : (96 + c);
    s_pt[lr * PSTR + col] = __floats2half2_rn(0.f, 0.f);
  }
  __syncthreads();

  // ---- Phase A: horizontal gaussian of {p,t,pp,tt,pt}, 4 outputs/group ----
#pragma unroll
  for (int i = 0; i < 3; ++i) {
    int g = tid + i * NT;              // group id, 816 total
    if (g < HR * 24) {
      int lr = g / 24, cg = g - lr * 24;
      int x0 = cg * 4;
      const uint32_t* row = reinterpret_cast<const uint32_t*>(&s_pt[lr * PSTR + x0]);
      uint4 A = reinterpret_cast<const uint4*>(row)[0];
      uint4 B = reinterpret_cast<const uint4*>(row)[1];
      uint4 C = reinterpret_cast<const uint4*>(row)[2];
      uint2 D = reinterpret_cast<const uint2*>(row)[6];
      uint32_t u[14] = {A.x, A.y, A.z, A.w, B.x, B.y, B.z, B.w,
                        C.x, C.y, C.z, C.w, D.x, D.y};
      float a[4]  = {0.f, 0.f, 0.f, 0.f};
      float bb[4] = {0.f, 0.f, 0.f, 0.f};
      float d[4]  = {0.f, 0.f, 0.f, 0.f};
      float e[4]  = {0.f, 0.f, 0.f, 0.f};
      float f5[4] = {0.f, 0.f, 0.f, 0.f};
#pragma unroll
      for (int t = 0; t < 14; ++t) {
        __half2 h = *reinterpret_cast<__half2*>(&u[t]);
        float2 v = __half22float2(h);
        float xx = v.x * v.x, yy = v.y * v.y, xy = v.x * v.y;
#pragma unroll
        for (int k = 0; k < 4; ++k) {
          const int j = t - k;         // compile-time after unroll
          if (j >= 0 && j < 11) {
            float w = G[j];
            a[k]  = fmaf(w, v.x, a[k]);
            bb[k] = fmaf(w, v.y, bb[k]);
            d[k]  = fmaf(w, xx, d[k]);
            e[k]  = fmaf(w, yy, e[k]);
            f5[k] = fmaf(w, xy, f5[k]);
          }
        }
      }
      int o = lr * PW + x0;
#pragma unroll
      for (int k = 0; k < 4; ++k) {
        s_ab[o + k] = __floats2half2_rn(a[k], bb[k]);
        s_de[o + k] = __floats2half2_rn(d[k], e[k]);
        s_c [o + k] = __float2half_rn(f5[k]);
      }
    }
  }
  __syncthreads();

  // ---- Phase B: vertical 11-row running box + SSIM (4 strips x 96 cols) ----
  float ssum = 0.f;
  {
    int strip = tid / PW;              // 0..3, 6 output rows each
    int x     = tid - strip * PW;
    int o0    = strip * 6;
    float sa = 0.f, sb = 0.f, sd = 0.f, se = 0.f, sc = 0.f;

#define RROW(HRI, OP) do { \
      int _i = (HRI) * PW + x; \
      float2 _va = __half22float2(s_ab[_i]); \
      float2 _vd = __half22float2(s_de[_i]); \
      float  _vc = __half2float(s_c[_i]); \
      sa OP _va.x; sb OP _va.y; sd OP _vd.x; se OP _vd.y; sc OP _vc; \
    } while (0)

#pragma unroll
    for (int r = 0; r < 10; ++r) RROW(o0 + r, +=);
#pragma unroll
    for (int i2 = 0; i2 < 6; ++i2) {
      int o = o0 + i2;
      RROW(o + 10, +=);                // window = h rows [o, o+10]
      float m11 = sa * sa, m22 = sb * sb, m12 = sa * sb;
      float num = (2.f * m12 + 1e-4f) * (2.f * (sc - m12) + 9e-4f);
      float den = (m11 + m22 + 1e-4f) * ((sd - m11) + (se - m22) + 9e-4f);
      ssum += __fdividef(num, den);
      RROW(o, -=);
    }
#undef RROW
  }

  // ---- block reduction -> per-block slot (no atomics) ----
  int lane = tid & 63, wv = tid >> 6;
#pragma unroll
  for (int o = 32; o; o >>= 1) {
    bce  += __shfl_down(bce, o);
    ts   += __shfl_down(ts, o);
    ssum += __shfl_down(ssum, o);
  }
  if (lane == 0) { red[wv][0] = bce; red[wv][1] = ts; red[wv][2] = ssum; }
  __syncthreads();
  if (tid == 0) {
    float A = 0.f, B = 0.f, C = 0.f;
#pragma unroll
    for (int w = 0; w < 6; ++w) { A += red[w][0]; B += red[w][1]; C += red[w][2]; }
    float* out = accum + (size_t)b * 4;
    out[0] = A; out[1] = B; out[2] = C;
  }
}

// masked mean over patches -> scalar (folds the 4 sub-block slots per patch)
__global__ __launch_bounds__(256) void kC(
    const float* __restrict__ accum, const int* __restrict__ mask,
    float* __restrict__ out, int N)
{
  int tid = threadIdx.x;
  float tot = 0.f, cnt = 0.f;
  const float inv = 1.f / (float)PIX;
  for (int i = tid; i < N; i += 256) {
    float bce = 0.f, tsv = 0.f, ssv = 0.f;
#pragma unroll
    for (int s = 0; s < 4; ++s) {
      const float* sl = accum + (size_t)(i * 4 + s) * 4;
      bce += sl[0]; tsv += sl[1]; ssv += sl[2];
    }
    bool valid = (mask[i] != 0) && (tsv >= 1e-6f);
    float loss = 0.5f * (bce * inv) + 0.5f * (1.f - ssv * inv);
    if (valid) { tot += loss; cnt += 1.f; }
  }
  __shared__ float sT[256], sC[256];
  sT[tid] = tot; sC[tid] = cnt;
  __syncthreads();
  for (int o = 128; o; o >>= 1) {
    if (tid < o) { sT[tid] += sT[tid + o]; sC[tid] += sC[tid + o]; }
    __syncthreads();
  }
  if (tid == 0) out[0] = (sC[0] > 0.f) ? (sT[0] / sC[0]) : 0.f;
}

extern "C" void kernel_launch(void* const* d_in, const int* in_sizes, int n_in,
                              void* d_out, int out_size, void* d_ws, size_t ws_size,
                              hipStream_t stream) {
  const float* pred = (const float*)d_in[0];
  const float* tgt  = (const float*)d_in[1];
  const int*   mask = (const int*)d_in[2];
  int N = in_sizes[2];  // 2048 patches

  float* accum = (float*)d_ws;  // [N*4][4] floats, every slot written by fused
  fused<<<N * 4, NT, 0, stream>>>(pred, tgt, accum);
  kC<<<1, 256, 0, stream>>>(accum, mask, (float*)d_out, N);
}

// Round 4
// 211.089 us; speedup vs baseline: 1.5634x; 1.2216x over previous
//
#include <hip/hip_runtime.h>
#include <hip/hip_fp16.h>
#include <stdint.h>

#define PW 96
#define PH 96
#define PIX 9216
#define OROWS 32          // owned rows per block (patch thirds)
#define SROWS 42          // staged rows incl. 5-row halo each side
#define PTSTR 100         // s_pt stride (half2 units) = 400 B, 16B-aligned rows
#define FSTR 112          // field stride (f16 units): cols = x in [-5, 106], 224 B/row
#define NT 384
#define NBLK 3

typedef _Float16 f16x8 __attribute__((ext_vector_type(8)));
typedef float f32x4 __attribute__((ext_vector_type(4)));

// normalized gaussian (WS=11, sigma=1.5, sum=1) — same literals verified R1-R3
__device__ __constant__ float d_G[11] = {
  1.02838e-03f, 7.59876e-03f, 3.60008e-02f, 1.09361e-01f, 2.13006e-01f,
  2.66012e-01f, 2.13006e-01f, 1.09361e-01f, 3.60008e-02f, 7.59876e-03f,
  1.02838e-03f};

__global__ __launch_bounds__(NT, 5) void fused(
    const float* __restrict__ pred, const float* __restrict__ tgt,
    float* __restrict__ accum)
{
  __shared__ __align__(16) __half2   s_pt[SROWS * PTSTR]; // (p,t) packed
  __shared__ __align__(16) _Float16  s_f[5][OROWS * FSTR]; // box fields
  __shared__ _Float16 s_gt[47];                            // g[k-n] table
  __shared__ float red[6][3];

  const int b   = blockIdx.x;
  const int pid = b / NBLK;
  const int sub = b - pid * NBLK;
  const int y0  = sub * OROWS;
  const int tid = threadIdx.x;

  const float4* p4 = reinterpret_cast<const float4*>(pred + (size_t)pid * PIX);
  const float4* t4 = reinterpret_cast<const float4*>(tgt  + (size_t)pid * PIX);

  // banded-Toeplitz weight table: s_gt[d+15] = g[d] for d in [0,10], else 0
  if (tid < 47) {
    int d = tid - 15;
    s_gt[tid] = (_Float16)((d >= 0 && d <= 10) ? d_G[d] : 0.f);
  }

  // ---- Phase 0: stage rows y0-5..y0+36 -> LDS half2; fused BCE on owned ----
  float bce = 0.f, ts = 0.f;
#pragma unroll
  for (int i = 0; i < 3; ++i) {
    int s = tid + i * NT;              // slot = (staged row, float4-col), 42*24=1008
    if (s < SROWS * 24) {
      int lr = s / 24, c = s - lr * 24;
      int gy = y0 + lr - 5;
      float4 vp = make_float4(0.f, 0.f, 0.f, 0.f);
      float4 vt = make_float4(0.f, 0.f, 0.f, 0.f);
      if (gy >= 0 && gy < PH) { vp = p4[gy * 24 + c]; vt = t4[gy * 24 + c]; }
      __half2 h0 = __floats2half2_rn(vp.x, vt.x);
      __half2 h1 = __floats2half2_rn(vp.y, vt.y);
      __half2 h2 = __floats2half2_rn(vp.z, vt.z);
      __half2 h3 = __floats2half2_rn(vp.w, vt.w);
      uint4 u = make_uint4(*reinterpret_cast<uint32_t*>(&h0),
                           *reinterpret_cast<uint32_t*>(&h1),
                           *reinterpret_cast<uint32_t*>(&h2),
                           *reinterpret_cast<uint32_t*>(&h3));
      *reinterpret_cast<uint4*>(&s_pt[lr * PTSTR + c * 4]) = u;
      if (lr >= 5 && lr < 5 + OROWS) { // owned rows
        const float pv[4] = {vp.x, vp.y, vp.z, vp.w};
        const float tv[4] = {vt.x, vt.y, vt.z, vt.w};
#pragma unroll
        for (int k = 0; k < 4; ++k) {
          float lp = fmaxf(__logf(pv[k]), -100.f);
          float l1 = fmaxf(__logf(1.f - pv[k]), -100.f);
          bce -= tv[k] * lp + (1.f - tv[k]) * l1;
          ts  += tv[k];
        }
      }
    }
  }
  __syncthreads();

  // ---- Phase A: vertical 11-row running box per column -> f16 fields ----
  {
    const int x   = tid % PW;
    const int seg = tid / PW;          // 0..3, 8 output rows each
    const int r0s = seg * 8;           // staged idx of local row (seg*8 - 5)
    float op[8], oq[8], opp[8], ott[8], opt[8];  // evict ring (static idx)
    op[0] = oq[0] = opp[0] = ott[0] = opt[0] = 0.f;
    float Sp = 0.f, St = 0.f, Spp = 0.f, Stt = 0.f, Spt = 0.f;
#pragma unroll
    for (int i = 0; i < 10; ++i) {     // init window (10 rows)
      float2 v = __half22float2(s_pt[(r0s + i) * PTSTR + x]);
      float a = v.x, t = v.y, aa = a * a, tt2 = t * t, at = a * t;
      Sp += a; St += t; Spp += aa; Stt += tt2; Spt += at;
      if (i < 7) { op[i+1] = a; oq[i+1] = t; opp[i+1] = aa; ott[i+1] = tt2; opt[i+1] = at; }
    }
#pragma unroll
    for (int i = 0; i < 8; ++i) {      // slide: +new row, -old row
      float2 v = __half22float2(s_pt[(r0s + 10 + i) * PTSTR + x]);
      float a = v.x, t = v.y, aa = a * a, tt2 = t * t, at = a * t;
      Sp += a - op[i]; St += t - oq[i]; Spp += aa - opp[i];
      Stt += tt2 - ott[i]; Spt += at - opt[i];
      int ob = (seg * 8 + i) * FSTR + 5 + x;
      s_f[0][ob] = (_Float16)Sp;
      s_f[1][ob] = (_Float16)St;
      s_f[2][ob] = (_Float16)Spp;
      s_f[3][ob] = (_Float16)Stt;
      s_f[4][ob] = (_Float16)Spt;
    }
  }
  // zero x-halo cols of the field arrays (idx 0..4 and 101..111)
  for (int i2 = tid; i2 < 5 * OROWS * 16; i2 += NT) {
    int f = i2 >> 9;                   // /512
    int rem = i2 & 511;
    int r = rem >> 4, c = rem & 15;
    int idx = (c < 5) ? c : (96 + c);
    s_f[f][r * FSTR + idx] = (_Float16)0.f;
  }
  __syncthreads();

  // ---- Phase B: MFMA horizontal gaussian + in-register SSIM ----
  const int lane = tid & 63;
  const int nn = lane & 15;
  const int qq = lane >> 4;
  f16x8 bf;                            // B(k,n) = g[k-n], k = 8*qq+j, n = nn
#pragma unroll
  for (int j = 0; j < 8; ++j) bf[j] = s_gt[8 * qq + j - nn + 15];

  const int wv = tid >> 6;             // wave 0..5 = x-tile
  float ssum = 0.f;
#pragma unroll
  for (int rt = 0; rt < 2; ++rt) {     // 2 row-tiles of 16
    const int abase = (rt * 16 + nn) * FSTR + wv * 16 + 8 * qq;
    f32x4 a0 = {0.f,0.f,0.f,0.f}, a1 = a0, a2 = a0, a3 = a0, a4 = a0;
    f16x8 f0 = *reinterpret_cast<const f16x8*>(&s_f[0][abase]);
    f16x8 f1 = *reinterpret_cast<const f16x8*>(&s_f[1][abase]);
    f16x8 f2 = *reinterpret_cast<const f16x8*>(&s_f[2][abase]);
    f16x8 f3 = *reinterpret_cast<const f16x8*>(&s_f[3][abase]);
    f16x8 f4 = *reinterpret_cast<const f16x8*>(&s_f[4][abase]);
    a0 = __builtin_amdgcn_mfma_f32_16x16x32_f16(f0, bf, a0, 0, 0, 0); // mu1
    a1 = __builtin_amdgcn_mfma_f32_16x16x32_f16(f1, bf, a1, 0, 0, 0); // mu2
    a2 = __builtin_amdgcn_mfma_f32_16x16x32_f16(f2, bf, a2, 0, 0, 0); // e11
    a3 = __builtin_amdgcn_mfma_f32_16x16x32_f16(f3, bf, a3, 0, 0, 0); // e22
    a4 = __builtin_amdgcn_mfma_f32_16x16x32_f16(f4, bf, a4, 0, 0, 0); // e12
#pragma unroll
    for (int r = 0; r < 4; ++r) {
      float mu1 = a0[r], mu2 = a1[r], e11 = a2[r], e22 = a3[r], e12 = a4[r];
      float m11 = mu1 * mu1, m22 = mu2 * mu2, m12 = mu1 * mu2;
      float num = (2.f * m12 + 1e-4f) * (2.f * (e12 - m12) + 9e-4f);
      float den = (m11 + m22 + 1e-4f) * ((e11 - m11) + (e22 - m22) + 9e-4f);
      ssum += __fdividef(num, den);
    }
  }

  // ---- block reduction -> per-block slot ----
#pragma unroll
  for (int o = 32; o; o >>= 1) {
    bce  += __shfl_down(bce, o);
    ts   += __shfl_down(ts, o);
    ssum += __shfl_down(ssum, o);
  }
  if (lane == 0) { red[wv][0] = bce; red[wv][1] = ts; red[wv][2] = ssum; }
  __syncthreads();
  if (tid == 0) {
    float A = 0.f, B = 0.f, C = 0.f;
#pragma unroll
    for (int w = 0; w < 6; ++w) { A += red[w][0]; B += red[w][1]; C += red[w][2]; }
    float* out = accum + (size_t)b * 4;
    out[0] = A; out[1] = B; out[2] = C;
  }
}

// masked mean over patches -> scalar (folds NBLK sub-block slots per patch)
__global__ __launch_bounds__(256) void kC(
    const float* __restrict__ accum, const int* __restrict__ mask,
    float* __restrict__ out, int N)
{
  int tid = threadIdx.x;
  float tot = 0.f, cnt = 0.f;
  const float inv = 1.f / (float)PIX;
  for (int i = tid; i < N; i += 256) {
    float bce = 0.f, tsv = 0.f, ssv = 0.f;
#pragma unroll
    for (int s = 0; s < NBLK; ++s) {
      const float* sl = accum + (size_t)(i * NBLK + s) * 4;
      bce += sl[0]; tsv += sl[1]; ssv += sl[2];
    }
    bool valid = (mask[i] != 0) && (tsv >= 1e-6f);
    float loss = 0.5f * (bce * inv) + 0.5f * (1.f - ssv * inv);
    if (valid) { tot += loss; cnt += 1.f; }
  }
  __shared__ float sT[256], sC[256];
  sT[tid] = tot; sC[tid] = cnt;
  __syncthreads();
  for (int o = 128; o; o >>= 1) {
    if (tid < o) { sT[tid] += sT[tid + o]; sC[tid] += sC[tid + o]; }
    __syncthreads();
  }
  if (tid == 0) out[0] = (sC[0] > 0.f) ? (sT[0] / sC[0]) : 0.f;
}

extern "C" void kernel_launch(void* const* d_in, const int* in_sizes, int n_in,
                              void* d_out, int out_size, void* d_ws, size_t ws_size,
                              hipStream_t stream) {
  const float* pred = (const float*)d_in[0];
  const float* tgt  = (const float*)d_in[1];
  const int*   mask = (const int*)d_in[2];
  int N = in_sizes[2];  // 2048 patches

  float* accum = (float*)d_ws;  // [N*NBLK][4] floats, each slot written by fused
  fused<<<N * NBLK, NT, 0, stream>>>(pred, tgt, accum);
  kC<<<1, 256, 0, stream>>>(accum, mask, (float*)d_out, N);
}